// Round 2
// baseline (2446.761 us; speedup 1.0000x reference)
//
#include <hip/hip_runtime.h>
#include <hip/hip_bf16.h>
#include <cstdint>

#define NHEAD 8
#define D1 64      // H1*C1
#define IN_F 128
#define NEG 0.2f

// ---------------- Kernel A: h1 = feat @ W1, a_src1/a_dst1 dots ----------------
__global__ __launch_bounds__(256) void k_gemm1(
    const float* __restrict__ feat,
    const float* __restrict__ W1,
    const float* __restrict__ att_s,
    const float* __restrict__ att_d,
    float* __restrict__ h1, float* __restrict__ a_src, float* __restrict__ a_dst,
    int N)
{
    __shared__ float ldsW[IN_F * D1];   // 32 KB
    __shared__ float ldsF[4][IN_F];     // 2 KB
    const int tid = threadIdx.x;
    for (int i = tid; i < IN_F * D1; i += 256) ldsW[i] = W1[i];
    const int r = tid >> 6, j = tid & 63;
    const float asw = att_s[j];
    const float adw = att_d[j];
    const int base = blockIdx.x * 4;
    for (int i = tid; i < 4 * IN_F; i += 256) {
        int rr = i >> 7, k = i & 127;
        int n = base + rr;
        ldsF[rr][k] = (n < N) ? feat[(size_t)n * IN_F + k] : 0.f;
    }
    __syncthreads();
    const int n = base + r;
    if (n < N) {
        float acc = 0.f;
        #pragma unroll 8
        for (int k = 0; k < IN_F; ++k)
            acc = fmaf(ldsF[r][k], ldsW[k * D1 + j], acc);
        h1[(size_t)n * D1 + j] = acc;
        float ps = acc * asw, pd = acc * adw;
        ps += __shfl_xor(ps, 1); pd += __shfl_xor(pd, 1);
        ps += __shfl_xor(ps, 2); pd += __shfl_xor(pd, 2);
        ps += __shfl_xor(ps, 4); pd += __shfl_xor(pd, 4);
        if ((j & 7) == 0) {
            int h = j >> 3;
            a_src[n * NHEAD + h] = ps;
            a_dst[n * NHEAD + h] = pd;
        }
    }
}

// ---------------- Kernel B1: denom1[d,h] += exp(leaky(a_s[s,h]+a_d[d,h])) ----------------
__global__ __launch_bounds__(256) void k_edge_den1(
    const int* __restrict__ src, const int* __restrict__ dst,
    const float* __restrict__ a_src, const float* __restrict__ a_dst,
    float* __restrict__ den, long long EH)
{
    long long gid = (long long)blockIdx.x * 256 + threadIdx.x;
    if (gid >= EH) return;
    int e = (int)(gid >> 3), h = (int)(gid & 7);
    int s = src[e], d = dst[e];
    float v = a_src[s * NHEAD + h] + a_dst[d * NHEAD + h];
    v = v > 0.f ? v : NEG * v;
    atomicAdd(&den[d * NHEAD + h], expf(v));
}

// ---------------- Kernel B2: out1[d,j] += h1[s,j] * alpha ----------------
__global__ __launch_bounds__(256) void k_edge_agg1(
    const int* __restrict__ src, const int* __restrict__ dst,
    const float* __restrict__ a_src, const float* __restrict__ a_dst,
    const float* __restrict__ den, const float* __restrict__ h1,
    float* __restrict__ out1, long long EJ)
{
    long long gid = (long long)blockIdx.x * 256 + threadIdx.x;
    if (gid >= EJ) return;
    int e = (int)(gid >> 6), j = (int)(gid & 63), h = j >> 3;
    int s = src[e], d = dst[e];
    float v = a_src[s * NHEAD + h] + a_dst[d * NHEAD + h];
    v = v > 0.f ? v : NEG * v;
    float alpha = expf(v) / den[d * NHEAD + h];
    atomicAdd(&out1[(size_t)d * D1 + j], h1[(size_t)s * D1 + j] * alpha);
}

// ---------------- Kernel C: x = elu(out1 + b1), in place ----------------
__global__ __launch_bounds__(256) void k_elu(
    float* __restrict__ x, const float* __restrict__ b1, long long n64)
{
    long long gid = (long long)blockIdx.x * 256 + threadIdx.x;
    if (gid >= n64) return;
    int j = (int)(gid & 63);
    float v = x[gid] + b1[j];
    x[gid] = v > 0.f ? v : expm1f(v);
}

// ---------------- Kernel D: h2 = x @ W2, a_src2/a_dst2 ----------------
__global__ __launch_bounds__(256) void k_gemm2(
    const float* __restrict__ x,
    const float* __restrict__ W2,
    const float* __restrict__ att_s,
    const float* __restrict__ att_d,
    float* __restrict__ h2, float* __restrict__ a_src, float* __restrict__ a_dst,
    int N)
{
    __shared__ float ldsW[64 * 64];   // 16 KB
    __shared__ float ldsX[4][64];
    const int tid = threadIdx.x;
    for (int i = tid; i < 64 * 64; i += 256) ldsW[i] = W2[i];
    const int r = tid >> 6, j = tid & 63;
    const float asw = att_s[j];
    const float adw = att_d[j];
    const int base = blockIdx.x * 4;
    const int n = base + r;
    ldsX[r][j] = (n < N) ? x[(size_t)n * 64 + j] : 0.f;
    __syncthreads();
    if (n < N) {
        float acc = 0.f;
        #pragma unroll 8
        for (int k = 0; k < 64; ++k)
            acc = fmaf(ldsX[r][k], ldsW[k * 64 + j], acc);
        h2[(size_t)n * 64 + j] = acc;
        float ps = acc * asw, pd = acc * adw;
        #pragma unroll
        for (int off = 1; off < 64; off <<= 1) {
            ps += __shfl_xor(ps, off);
            pd += __shfl_xor(pd, off);
        }
        if (j == 0) { a_src[n] = ps; a_dst[n] = pd; }
    }
}

// ---------------- Kernel E: denom2[d] ----------------
__global__ __launch_bounds__(256) void k_edge_den2(
    const int* __restrict__ src, const int* __restrict__ dst,
    const float* __restrict__ a_src, const float* __restrict__ a_dst,
    float* __restrict__ den, int E)
{
    int e = blockIdx.x * 256 + threadIdx.x;
    if (e >= E) return;
    float v = a_src[src[e]] + a_dst[dst[e]];
    v = v > 0.f ? v : NEG * v;
    atomicAdd(&den[dst[e]], expf(v));
}

// ---------------- Kernel F: out2[d,j] += h2[s,j]*alpha ----------------
__global__ __launch_bounds__(256) void k_edge_agg2(
    const int* __restrict__ src, const int* __restrict__ dst,
    const float* __restrict__ a_src, const float* __restrict__ a_dst,
    const float* __restrict__ den, const float* __restrict__ h2,
    float* __restrict__ out2, long long EJ)
{
    long long gid = (long long)blockIdx.x * 256 + threadIdx.x;
    if (gid >= EJ) return;
    int e = (int)(gid >> 6), j = (int)(gid & 63);
    int s = src[e], d = dst[e];
    float v = a_src[s] + a_dst[d];
    v = v > 0.f ? v : NEG * v;
    float alpha = expf(v) / den[d];
    atomicAdd(&out2[(size_t)d * 64 + j], h2[(size_t)s * 64 + j] * alpha);
}

// ---------------- Kernel G: log-softmax, NLL, argmax, label copy ----------------
__global__ __launch_bounds__(256) void k_final(
    const float* __restrict__ out2, const float* __restrict__ b2,
    const int* __restrict__ label,
    float* __restrict__ dout, double* __restrict__ lossacc, int N)
{
    const int tid = threadIdx.x;
    const int r = tid >> 6, j = tid & 63;
    const int n = blockIdx.x * 4 + r;
    if (n >= N) return;
    float sc = out2[(size_t)n * 64 + j] + b2[j];
    // argmax with lowest-index tie-break (matches np.argmax)
    float mv = sc; int mi = j;
    #pragma unroll
    for (int off = 1; off < 64; off <<= 1) {
        float ov = __shfl_xor(mv, off);
        int oi = __shfl_xor(mi, off);
        if (ov > mv || (ov == mv && oi < mi)) { mv = ov; mi = oi; }
    }
    float se = expf(sc - mv);
    #pragma unroll
    for (int off = 1; off < 64; off <<= 1) se += __shfl_xor(se, off);
    int lab = label[n];
    float sl = __shfl(sc, lab);
    if (j == 0) {
        float nll = mv + logf(se) - sl;
        atomicAdd(lossacc, (double)nll);
        dout[1 + n] = (float)mi;
        dout[1 + (size_t)N + n] = (float)lab;
    }
}

__global__ void k_loss(const double* __restrict__ acc, float* __restrict__ dout, int N)
{
    dout[0] = (float)(*acc / (double)N);
}

extern "C" void kernel_launch(void* const* d_in, const int* in_sizes, int n_in,
                              void* d_out, int out_size, void* d_ws, size_t ws_size,
                              hipStream_t stream)
{
    const float* feat   = (const float*)d_in[1];
    const int*   edge   = (const int*)d_in[2];
    const int*   label  = (const int*)d_in[4];
    const float* W1     = (const float*)d_in[5];
    const float* att_s1 = (const float*)d_in[6];
    const float* att_d1 = (const float*)d_in[7];
    const float* b1     = (const float*)d_in[8];
    const float* W2     = (const float*)d_in[9];
    const float* att_s2 = (const float*)d_in[10];
    const float* att_d2 = (const float*)d_in[11];
    const float* b2     = (const float*)d_in[12];

    const int N = in_sizes[0];
    const int E = in_sizes[2] / 2;
    const int* src = edge;
    const int* dst = edge + E;

    // workspace layout (h1 buffer is reused as out2 accumulator after gemm2)
    float* h1   = (float*)d_ws;               // N*64  (later: out2 accumulator / scores)
    float* out1 = h1   + (size_t)N * 64;      // N*64  (later: x in place)
    float* h2   = out1 + (size_t)N * 64;      // N*64
    float* a_s1 = h2   + (size_t)N * 64;      // N*8
    float* a_d1 = a_s1 + (size_t)N * 8;       // N*8
    float* den1 = a_d1 + (size_t)N * 8;       // N*8
    float* a_s2 = den1 + (size_t)N * 8;       // N
    float* a_d2 = a_s2 + N;                   // N
    float* den2 = a_d2 + N;                   // N
    double* lossacc = (double*)(((uintptr_t)(den2 + N) + 7) & ~(uintptr_t)7);

    float* out = (float*)d_out;

    hipMemsetAsync(out1, 0, (size_t)N * 64 * sizeof(float), stream);
    hipMemsetAsync(den1, 0, (size_t)N * 8 * sizeof(float), stream);
    hipMemsetAsync(den2, 0, (size_t)N * sizeof(float), stream);
    hipMemsetAsync(lossacc, 0, sizeof(double), stream);

    k_gemm1<<<(N + 3) / 4, 256, 0, stream>>>(feat, W1, att_s1, att_d1, h1, a_s1, a_d1, N);

    long long EH = (long long)E * 8;
    k_edge_den1<<<(unsigned)((EH + 255) / 256), 256, 0, stream>>>(src, dst, a_s1, a_d1, den1, EH);

    long long EJ = (long long)E * 64;
    k_edge_agg1<<<(unsigned)((EJ + 255) / 256), 256, 0, stream>>>(src, dst, a_s1, a_d1, den1, h1, out1, EJ);

    long long N64 = (long long)N * 64;
    k_elu<<<(unsigned)((N64 + 255) / 256), 256, 0, stream>>>(out1, b1, N64);

    k_gemm2<<<(N + 3) / 4, 256, 0, stream>>>(out1, W2, att_s2, att_d2, h2, a_s2, a_d2, N);

    // h1 is dead now; reuse as out2 accumulator
    hipMemsetAsync(h1, 0, (size_t)N * 64 * sizeof(float), stream);

    k_edge_den2<<<(E + 255) / 256, 256, 0, stream>>>(src, dst, a_s2, a_d2, den2, E);
    k_edge_agg2<<<(unsigned)((EJ + 255) / 256), 256, 0, stream>>>(src, dst, a_s2, a_d2, den2, h2, h1, EJ);

    k_final<<<(N + 3) / 4, 256, 0, stream>>>(h1, b2, label, out, lossacc, N);
    k_loss<<<1, 1, 0, stream>>>(lossacc, out, N);
}

// Round 3
// 1258.051 us; speedup vs baseline: 1.9449x; 1.9449x over previous
//
#include <hip/hip_runtime.h>
#include <hip/hip_bf16.h>
#include <cstdint>

#define NHEAD 8
#define D1 64      // H1*C1
#define IN_F 128
#define NEG 0.2f
#define NBINS 256  // loss partial-sum bins (breaks same-address atomic serialization)

// ---------------- Kernel A: h1 = feat @ W1, a_src1/a_dst1 dots ----------------
__global__ __launch_bounds__(256) void k_gemm1(
    const float* __restrict__ feat,
    const float* __restrict__ W1,
    const float* __restrict__ att_s,
    const float* __restrict__ att_d,
    float* __restrict__ h1, float* __restrict__ a_src, float* __restrict__ a_dst,
    int N)
{
    __shared__ float ldsW[IN_F * D1];   // 32 KB
    __shared__ float ldsF[4][IN_F];     // 2 KB
    const int tid = threadIdx.x;
    for (int i = tid; i < IN_F * D1; i += 256) ldsW[i] = W1[i];
    const int r = tid >> 6, j = tid & 63;
    const float asw = att_s[j];
    const float adw = att_d[j];
    const int base = blockIdx.x * 4;
    for (int i = tid; i < 4 * IN_F; i += 256) {
        int rr = i >> 7, k = i & 127;
        int n = base + rr;
        ldsF[rr][k] = (n < N) ? feat[(size_t)n * IN_F + k] : 0.f;
    }
    __syncthreads();
    const int n = base + r;
    if (n < N) {
        float acc = 0.f;
        #pragma unroll 8
        for (int k = 0; k < IN_F; ++k)
            acc = fmaf(ldsF[r][k], ldsW[k * D1 + j], acc);
        h1[(size_t)n * D1 + j] = acc;
        float ps = acc * asw, pd = acc * adw;
        ps += __shfl_xor(ps, 1); pd += __shfl_xor(pd, 1);
        ps += __shfl_xor(ps, 2); pd += __shfl_xor(pd, 2);
        ps += __shfl_xor(ps, 4); pd += __shfl_xor(pd, 4);
        if ((j & 7) == 0) {
            int h = j >> 3;
            a_src[n * NHEAD + h] = ps;
            a_dst[n * NHEAD + h] = pd;
        }
    }
}

// ---------------- Kernel B1: denom1[d,h] += exp(leaky(a_s[s,h]+a_d[d,h])) ----------------
__global__ __launch_bounds__(256) void k_edge_den1(
    const int* __restrict__ src, const int* __restrict__ dst,
    const float* __restrict__ a_src, const float* __restrict__ a_dst,
    float* __restrict__ den, long long EH)
{
    long long gid = (long long)blockIdx.x * 256 + threadIdx.x;
    if (gid >= EH) return;
    int e = (int)(gid >> 3), h = (int)(gid & 7);
    int s = src[e], d = dst[e];
    float v = a_src[s * NHEAD + h] + a_dst[d * NHEAD + h];
    v = v > 0.f ? v : NEG * v;
    atomicAdd(&den[d * NHEAD + h], expf(v));
}

// ---------------- Kernel B2: out1[d,j] += h1[s,j] * alpha ----------------
__global__ __launch_bounds__(256) void k_edge_agg1(
    const int* __restrict__ src, const int* __restrict__ dst,
    const float* __restrict__ a_src, const float* __restrict__ a_dst,
    const float* __restrict__ den, const float* __restrict__ h1,
    float* __restrict__ out1, long long EJ)
{
    long long gid = (long long)blockIdx.x * 256 + threadIdx.x;
    if (gid >= EJ) return;
    int e = (int)(gid >> 6), j = (int)(gid & 63), h = j >> 3;
    int s = src[e], d = dst[e];
    float v = a_src[s * NHEAD + h] + a_dst[d * NHEAD + h];
    v = v > 0.f ? v : NEG * v;
    float alpha = expf(v) / den[d * NHEAD + h];
    atomicAdd(&out1[(size_t)d * D1 + j], h1[(size_t)s * D1 + j] * alpha);
}

// ---------------- Kernel C: x = elu(out1 + b1), in place ----------------
__global__ __launch_bounds__(256) void k_elu(
    float* __restrict__ x, const float* __restrict__ b1, long long n64)
{
    long long gid = (long long)blockIdx.x * 256 + threadIdx.x;
    if (gid >= n64) return;
    int j = (int)(gid & 63);
    float v = x[gid] + b1[j];
    x[gid] = v > 0.f ? v : expm1f(v);
}

// ---------------- Kernel D: h2 = x @ W2, a_src2/a_dst2 ----------------
__global__ __launch_bounds__(256) void k_gemm2(
    const float* __restrict__ x,
    const float* __restrict__ W2,
    const float* __restrict__ att_s,
    const float* __restrict__ att_d,
    float* __restrict__ h2, float* __restrict__ a_src, float* __restrict__ a_dst,
    int N)
{
    __shared__ float ldsW[64 * 64];   // 16 KB
    __shared__ float ldsX[4][64];
    const int tid = threadIdx.x;
    for (int i = tid; i < 64 * 64; i += 256) ldsW[i] = W2[i];
    const int r = tid >> 6, j = tid & 63;
    const float asw = att_s[j];
    const float adw = att_d[j];
    const int base = blockIdx.x * 4;
    const int n = base + r;
    ldsX[r][j] = (n < N) ? x[(size_t)n * 64 + j] : 0.f;
    __syncthreads();
    if (n < N) {
        float acc = 0.f;
        #pragma unroll 8
        for (int k = 0; k < 64; ++k)
            acc = fmaf(ldsX[r][k], ldsW[k * 64 + j], acc);
        h2[(size_t)n * 64 + j] = acc;
        float ps = acc * asw, pd = acc * adw;
        #pragma unroll
        for (int off = 1; off < 64; off <<= 1) {
            ps += __shfl_xor(ps, off);
            pd += __shfl_xor(pd, off);
        }
        if (j == 0) { a_src[n] = ps; a_dst[n] = pd; }
    }
}

// ---------------- Kernel E: denom2[d] ----------------
__global__ __launch_bounds__(256) void k_edge_den2(
    const int* __restrict__ src, const int* __restrict__ dst,
    const float* __restrict__ a_src, const float* __restrict__ a_dst,
    float* __restrict__ den, int E)
{
    int e = blockIdx.x * 256 + threadIdx.x;
    if (e >= E) return;
    float v = a_src[src[e]] + a_dst[dst[e]];
    v = v > 0.f ? v : NEG * v;
    atomicAdd(&den[dst[e]], expf(v));
}

// ---------------- Kernel F: out2[d,j] += h2[s,j]*alpha ----------------
__global__ __launch_bounds__(256) void k_edge_agg2(
    const int* __restrict__ src, const int* __restrict__ dst,
    const float* __restrict__ a_src, const float* __restrict__ a_dst,
    const float* __restrict__ den, const float* __restrict__ h2,
    float* __restrict__ out2, long long EJ)
{
    long long gid = (long long)blockIdx.x * 256 + threadIdx.x;
    if (gid >= EJ) return;
    int e = (int)(gid >> 6), j = (int)(gid & 63);
    int s = src[e], d = dst[e];
    float v = a_src[s] + a_dst[d];
    v = v > 0.f ? v : NEG * v;
    float alpha = expf(v) / den[d];
    atomicAdd(&out2[(size_t)d * 64 + j], h2[(size_t)s * 64 + j] * alpha);
}

// ---------------- Kernel G: log-softmax, NLL, argmax, label copy ----------------
// Loss: per-block LDS reduction -> one fp64 atomic into bins[blockIdx&255].
// (Round-2 lesson: 100k same-address fp64 atomics serialized at ~12ns each = 1.2ms.)
__global__ __launch_bounds__(256) void k_final(
    const float* __restrict__ out2, const float* __restrict__ b2,
    const int* __restrict__ label,
    float* __restrict__ dout, double* __restrict__ bins, int N)
{
    __shared__ float snll[4];
    const int tid = threadIdx.x;
    const int r = tid >> 6, j = tid & 63;
    const int n = blockIdx.x * 4 + r;
    if (j == 0) snll[r] = 0.f;
    float sc = (n < N) ? out2[(size_t)n * 64 + j] + b2[j] : 0.f;
    // argmax with lowest-index tie-break (matches np.argmax)
    float mv = sc; int mi = j;
    #pragma unroll
    for (int off = 1; off < 64; off <<= 1) {
        float ov = __shfl_xor(mv, off);
        int oi = __shfl_xor(mi, off);
        if (ov > mv || (ov == mv && oi < mi)) { mv = ov; mi = oi; }
    }
    float se = expf(sc - mv);
    #pragma unroll
    for (int off = 1; off < 64; off <<= 1) se += __shfl_xor(se, off);
    int lab = (n < N) ? label[n] : 0;
    float sl = __shfl(sc, lab);
    if (j == 0 && n < N) {
        snll[r] = mv + logf(se) - sl;
        dout[1 + n] = (float)mi;
        dout[1 + (size_t)N + n] = (float)lab;
    }
    __syncthreads();
    if (tid == 0) {
        double bsum = (double)snll[0] + (double)snll[1]
                    + (double)snll[2] + (double)snll[3];
        atomicAdd(&bins[blockIdx.x & (NBINS - 1)], bsum);
    }
}

// Single block of 256: reduce NBINS doubles -> loss
__global__ __launch_bounds__(256) void k_loss(
    const double* __restrict__ bins, float* __restrict__ dout, int N)
{
    __shared__ double sw[4];
    const int tid = threadIdx.x;
    double v = bins[tid];
    #pragma unroll
    for (int off = 1; off < 64; off <<= 1) v += __shfl_xor(v, off);
    if ((tid & 63) == 0) sw[tid >> 6] = v;
    __syncthreads();
    if (tid == 0)
        dout[0] = (float)((sw[0] + sw[1] + sw[2] + sw[3]) / (double)N);
}

extern "C" void kernel_launch(void* const* d_in, const int* in_sizes, int n_in,
                              void* d_out, int out_size, void* d_ws, size_t ws_size,
                              hipStream_t stream)
{
    const float* feat   = (const float*)d_in[1];
    const int*   edge   = (const int*)d_in[2];
    const int*   label  = (const int*)d_in[4];
    const float* W1     = (const float*)d_in[5];
    const float* att_s1 = (const float*)d_in[6];
    const float* att_d1 = (const float*)d_in[7];
    const float* b1     = (const float*)d_in[8];
    const float* W2     = (const float*)d_in[9];
    const float* att_s2 = (const float*)d_in[10];
    const float* att_d2 = (const float*)d_in[11];
    const float* b2     = (const float*)d_in[12];

    const int N = in_sizes[0];
    const int E = in_sizes[2] / 2;
    const int* src = edge;
    const int* dst = edge + E;

    // workspace layout (h1 buffer is reused as out2 accumulator after gemm2)
    float* h1   = (float*)d_ws;               // N*64  (later: out2 accumulator / scores)
    float* out1 = h1   + (size_t)N * 64;      // N*64  (later: x in place)
    float* h2   = out1 + (size_t)N * 64;      // N*64
    float* a_s1 = h2   + (size_t)N * 64;      // N*8
    float* a_d1 = a_s1 + (size_t)N * 8;       // N*8
    float* den1 = a_d1 + (size_t)N * 8;       // N*8
    float* a_s2 = den1 + (size_t)N * 8;       // N
    float* a_d2 = a_s2 + N;                   // N
    float* den2 = a_d2 + N;                   // N
    double* bins = (double*)(((uintptr_t)(den2 + N) + 7) & ~(uintptr_t)7); // NBINS doubles

    float* out = (float*)d_out;

    hipMemsetAsync(out1, 0, (size_t)N * 64 * sizeof(float), stream);
    hipMemsetAsync(den1, 0, (size_t)N * 8 * sizeof(float), stream);
    hipMemsetAsync(den2, 0, (size_t)N * sizeof(float), stream);
    hipMemsetAsync(bins, 0, NBINS * sizeof(double), stream);

    k_gemm1<<<(N + 3) / 4, 256, 0, stream>>>(feat, W1, att_s1, att_d1, h1, a_s1, a_d1, N);

    long long EH = (long long)E * 8;
    k_edge_den1<<<(unsigned)((EH + 255) / 256), 256, 0, stream>>>(src, dst, a_s1, a_d1, den1, EH);

    long long EJ = (long long)E * 64;
    k_edge_agg1<<<(unsigned)((EJ + 255) / 256), 256, 0, stream>>>(src, dst, a_s1, a_d1, den1, h1, out1, EJ);

    long long N64 = (long long)N * 64;
    k_elu<<<(unsigned)((N64 + 255) / 256), 256, 0, stream>>>(out1, b1, N64);

    k_gemm2<<<(N + 3) / 4, 256, 0, stream>>>(out1, W2, att_s2, att_d2, h2, a_s2, a_d2, N);

    // h1 is dead now; reuse as out2 accumulator
    hipMemsetAsync(h1, 0, (size_t)N * 64 * sizeof(float), stream);

    k_edge_den2<<<(E + 255) / 256, 256, 0, stream>>>(src, dst, a_s2, a_d2, den2, E);
    k_edge_agg2<<<(unsigned)((EJ + 255) / 256), 256, 0, stream>>>(src, dst, a_s2, a_d2, den2, h2, h1, EJ);

    k_final<<<(N + 3) / 4, 256, 0, stream>>>(h1, b2, label, out, bins, N);
    k_loss<<<1, 256, 0, stream>>>(bins, out, N);
}

// Round 4
// 730.133 us; speedup vs baseline: 3.3511x; 1.7230x over previous
//
#include <hip/hip_runtime.h>
#include <cstdint>

#define NHEAD 8
#define D1 64      // H1*C1
#define IN_F 128
#define NEG 0.2f
#define NBINS 256  // loss partial-sum bins

// ---------------- Kernel A: h1 = feat @ W1, a_src1/a_dst1 dots ----------------
__global__ __launch_bounds__(256) void k_gemm1(
    const float* __restrict__ feat,
    const float* __restrict__ W1,
    const float* __restrict__ att_s,
    const float* __restrict__ att_d,
    float* __restrict__ h1, float* __restrict__ a_src, float* __restrict__ a_dst,
    int N)
{
    __shared__ float ldsW[IN_F * D1];   // 32 KB
    __shared__ float ldsF[4][IN_F];     // 2 KB
    const int tid = threadIdx.x;
    for (int i = tid; i < IN_F * D1; i += 256) ldsW[i] = W1[i];
    const int r = tid >> 6, j = tid & 63;
    const float asw = att_s[j];
    const float adw = att_d[j];
    const int base = blockIdx.x * 4;
    for (int i = tid; i < 4 * IN_F; i += 256) {
        int rr = i >> 7, k = i & 127;
        int n = base + rr;
        ldsF[rr][k] = (n < N) ? feat[(size_t)n * IN_F + k] : 0.f;
    }
    __syncthreads();
    const int n = base + r;
    if (n < N) {
        float acc = 0.f;
        #pragma unroll 8
        for (int k = 0; k < IN_F; ++k)
            acc = fmaf(ldsF[r][k], ldsW[k * D1 + j], acc);
        h1[(size_t)n * D1 + j] = acc;
        float ps = acc * asw, pd = acc * adw;
        ps += __shfl_xor(ps, 1); pd += __shfl_xor(pd, 1);
        ps += __shfl_xor(ps, 2); pd += __shfl_xor(pd, 2);
        ps += __shfl_xor(ps, 4); pd += __shfl_xor(pd, 4);
        if ((j & 7) == 0) {
            int h = j >> 3;
            a_src[n * NHEAD + h] = ps;
            a_dst[n * NHEAD + h] = pd;
        }
    }
}

// ---------------- CSR build: histogram / scan / fill ----------------
__global__ __launch_bounds__(256) void k_hist(
    const int* __restrict__ dst, int* __restrict__ deg, int E)
{
    int e = blockIdx.x * 256 + threadIdx.x;
    if (e < E) atomicAdd(&deg[dst[e]], 1);
}

__device__ __forceinline__ int block_incl_scan(int v, int tid, int* lds4)
{
    int lane = tid & 63, w = tid >> 6;
    #pragma unroll
    for (int off = 1; off < 64; off <<= 1) {
        int t = __shfl_up(v, off);
        if (lane >= off) v += t;
    }
    if (lane == 63) lds4[w] = v;
    __syncthreads();
    int add = 0;
    #pragma unroll
    for (int i = 0; i < 4; ++i)
        if (i < w) add += lds4[i];
    __syncthreads();
    return v + add;
}

__global__ __launch_bounds__(256) void k_scan1(
    const int* __restrict__ deg, int* __restrict__ locx, int* __restrict__ bsum, int N)
{
    __shared__ int lds4[4];
    int i = blockIdx.x * 256 + threadIdx.x;
    int v = (i < N) ? deg[i] : 0;
    int incl = block_incl_scan(v, threadIdx.x, lds4);
    if (i < N) locx[i] = incl - v;
    if (threadIdx.x == 255) bsum[blockIdx.x] = incl;
}

__global__ __launch_bounds__(256) void k_scan2(int* __restrict__ bsum, int nblk)
{
    __shared__ int lds4[4];
    __shared__ int carry;
    if (threadIdx.x == 0) carry = 0;
    __syncthreads();
    for (int base = 0; base < nblk; base += 256) {
        int i = base + threadIdx.x;
        int v = (i < nblk) ? bsum[i] : 0;
        int incl = block_incl_scan(v, threadIdx.x, lds4);
        int c = carry;
        __syncthreads();
        if (i < nblk) bsum[i] = incl - v + c;   // exclusive offset of block i
        if (threadIdx.x == 255) carry = c + incl;
        __syncthreads();
    }
}

__global__ __launch_bounds__(256) void k_scan3(
    const int* __restrict__ locx, const int* __restrict__ bsum,
    int* __restrict__ offs, int* __restrict__ cur, int N)
{
    int i = blockIdx.x * 256 + threadIdx.x;
    if (i < N) {
        int o = locx[i] + bsum[i >> 8];
        offs[i] = o;
        cur[i] = o;
    }
}

__global__ __launch_bounds__(256) void k_fill(
    const int* __restrict__ src, const int* __restrict__ dst,
    int* __restrict__ cur, int* __restrict__ srcs, int E)
{
    int e = blockIdx.x * 256 + threadIdx.x;
    if (e < E) {
        int p = atomicAdd(&cur[dst[e]], 1);
        srcs[p] = src[e];
    }
}

// ---------------- Layer-1 aggregation, dst-grouped, fused norm+bias+ELU ----------------
// out[d,j] = elu( (Σ_e exp(leaky(a_s[s,h]+a_d[d,h]))·h1[s,j]) / (Σ_e exp(..)) + b1[j] )
__global__ __launch_bounds__(256) void k_agg1(
    const int* __restrict__ deg, const int* __restrict__ offs,
    const int* __restrict__ srcs,
    const float* __restrict__ a_s, const float* __restrict__ a_d,
    const float* __restrict__ h1, const float* __restrict__ b1,
    float* __restrict__ x, int N)
{
    const int tid = threadIdx.x, w = tid >> 6, j = tid & 63, h = j >> 3;
    const int n = blockIdx.x * 4 + w;
    if (n >= N) return;
    const int rlen = deg[n], row = offs[n];
    const float ad = a_d[n * NHEAD + h];
    float acc = 0.f, den = 0.f;
    for (int base = 0; base < rlen; base += 64) {
        int m = rlen - base; if (m > 64) m = 64;
        int myS = (j < m) ? srcs[row + base + j] : 0;
        for (int k = 0; k < m; ++k) {
            int s = __shfl(myS, k);
            float v = a_s[s * NHEAD + h] + ad;
            v = v > 0.f ? v : NEG * v;
            float ex = expf(v);
            den += ex;                                     // lanes of a head all equal -> per-head denom
            acc = fmaf(ex, h1[(size_t)s * D1 + j], acc);
        }
    }
    float o = acc / den + b1[j];
    x[(size_t)n * D1 + j] = o > 0.f ? o : expm1f(o);
}

// ---------------- Kernel D: h2 = x @ W2, a_src2/a_dst2 ----------------
__global__ __launch_bounds__(256) void k_gemm2(
    const float* __restrict__ x,
    const float* __restrict__ W2,
    const float* __restrict__ att_s,
    const float* __restrict__ att_d,
    float* __restrict__ h2, float* __restrict__ a_src, float* __restrict__ a_dst,
    int N)
{
    __shared__ float ldsW[64 * 64];   // 16 KB
    __shared__ float ldsX[4][64];
    const int tid = threadIdx.x;
    for (int i = tid; i < 64 * 64; i += 256) ldsW[i] = W2[i];
    const int r = tid >> 6, j = tid & 63;
    const float asw = att_s[j];
    const float adw = att_d[j];
    const int base = blockIdx.x * 4;
    const int n = base + r;
    ldsX[r][j] = (n < N) ? x[(size_t)n * 64 + j] : 0.f;
    __syncthreads();
    if (n < N) {
        float acc = 0.f;
        #pragma unroll 8
        for (int k = 0; k < 64; ++k)
            acc = fmaf(ldsX[r][k], ldsW[k * 64 + j], acc);
        h2[(size_t)n * 64 + j] = acc;
        float ps = acc * asw, pd = acc * adw;
        #pragma unroll
        for (int off = 1; off < 64; off <<= 1) {
            ps += __shfl_xor(ps, off);
            pd += __shfl_xor(pd, off);
        }
        if (j == 0) { a_src[n] = ps; a_dst[n] = pd; }
    }
}

// ---------------- Layer-2 aggregation + bias + log-softmax + argmax + NLL ----------------
__global__ __launch_bounds__(256) void k_agg2(
    const int* __restrict__ deg, const int* __restrict__ offs,
    const int* __restrict__ srcs,
    const float* __restrict__ a_s, const float* __restrict__ a_d,
    const float* __restrict__ h2, const float* __restrict__ b2,
    const int* __restrict__ label,
    float* __restrict__ dout, double* __restrict__ bins, int N)
{
    __shared__ float snll[4];
    const int tid = threadIdx.x, w = tid >> 6, j = tid & 63;
    const int n = blockIdx.x * 4 + w;
    if (j == 0) snll[w] = 0.f;
    if (n < N) {
        const int rlen = deg[n], row = offs[n];
        const float ad = a_d[n];
        float acc = 0.f, den = 0.f;
        for (int base = 0; base < rlen; base += 64) {
            int m = rlen - base; if (m > 64) m = 64;
            int myS = (j < m) ? srcs[row + base + j] : 0;
            for (int k = 0; k < m; ++k) {
                int s = __shfl(myS, k);
                float v = a_s[s] + ad;
                v = v > 0.f ? v : NEG * v;
                float ex = expf(v);
                den += ex;
                acc = fmaf(ex, h2[(size_t)s * 64 + j], acc);
            }
        }
        float sc = acc / den + b2[j];
        // argmax, lowest-index tie-break (np.argmax)
        float mv = sc; int mi = j;
        #pragma unroll
        for (int off = 1; off < 64; off <<= 1) {
            float ov = __shfl_xor(mv, off);
            int oi = __shfl_xor(mi, off);
            if (ov > mv || (ov == mv && oi < mi)) { mv = ov; mi = oi; }
        }
        float se = expf(sc - mv);
        #pragma unroll
        for (int off = 1; off < 64; off <<= 1) se += __shfl_xor(se, off);
        int lab = label[n];
        float sl = __shfl(sc, lab);
        if (j == 0) {
            snll[w] = mv + logf(se) - sl;
            dout[1 + n] = (float)mi;
            dout[1 + (size_t)N + n] = (float)lab;
        }
    }
    __syncthreads();
    if (tid == 0) {
        double bsum = (double)snll[0] + (double)snll[1]
                    + (double)snll[2] + (double)snll[3];
        atomicAdd(&bins[blockIdx.x & (NBINS - 1)], bsum);
    }
}

// Single block of 256: reduce NBINS doubles -> loss
__global__ __launch_bounds__(256) void k_loss(
    const double* __restrict__ bins, float* __restrict__ dout, int N)
{
    __shared__ double sw[4];
    const int tid = threadIdx.x;
    double v = bins[tid];
    #pragma unroll
    for (int off = 1; off < 64; off <<= 1) v += __shfl_xor(v, off);
    if ((tid & 63) == 0) sw[tid >> 6] = v;
    __syncthreads();
    if (tid == 0)
        dout[0] = (float)((sw[0] + sw[1] + sw[2] + sw[3]) / (double)N);
}

extern "C" void kernel_launch(void* const* d_in, const int* in_sizes, int n_in,
                              void* d_out, int out_size, void* d_ws, size_t ws_size,
                              hipStream_t stream)
{
    const float* feat   = (const float*)d_in[1];
    const int*   edge   = (const int*)d_in[2];
    const int*   label  = (const int*)d_in[4];
    const float* W1     = (const float*)d_in[5];
    const float* att_s1 = (const float*)d_in[6];
    const float* att_d1 = (const float*)d_in[7];
    const float* b1     = (const float*)d_in[8];
    const float* W2     = (const float*)d_in[9];
    const float* att_s2 = (const float*)d_in[10];
    const float* att_d2 = (const float*)d_in[11];
    const float* b2     = (const float*)d_in[12];

    const int N = in_sizes[0];
    const int E = in_sizes[2] / 2;
    const int* src = edge;
    const int* dst = edge + E;

    // workspace layout (~66 MB):
    float* bufA = (float*)d_ws;               // N*64: h1, later reused as h2
    float* bufB = bufA + (size_t)N * 64;      // N*64: x (elu output)
    float* a_s1 = bufB + (size_t)N * 64;      // N*8 (layer2 reuses: a_s2=[0..N), a_d2=[N..2N))
    float* a_d1 = a_s1 + (size_t)N * 8;       // N*8
    int*   deg  = (int*)(a_d1 + (size_t)N * 8); // N
    int*   offs = deg + N;                    // N
    int*   cur  = offs + N;                   // N
    int*   srcs = cur + N;                    // E
    int*   locx = srcs + E;                   // N (scan scratch)
    int*   bsum = locx + N;                   // nblk (scan scratch)
    double* bins = (double*)(((uintptr_t)(bsum + ((N + 255) / 256) + 1) + 7) & ~(uintptr_t)7);

    float* a_s2 = a_s1;
    float* a_d2 = a_s1 + N;

    float* out = (float*)d_out;

    const int nblk = (N + 255) / 256;
    const int egrid = (E + 255) / 256;

    hipMemsetAsync(deg, 0, (size_t)N * sizeof(int), stream);
    hipMemsetAsync(bins, 0, NBINS * sizeof(double), stream);

    // CSR build (graph identical for both layers; rebuilt every call — no static state)
    k_hist <<<egrid, 256, 0, stream>>>(dst, deg, E);
    k_scan1<<<nblk, 256, 0, stream>>>(deg, locx, bsum, N);
    k_scan2<<<1, 256, 0, stream>>>(bsum, nblk);
    k_scan3<<<nblk, 256, 0, stream>>>(locx, bsum, offs, cur, N);
    k_fill <<<egrid, 256, 0, stream>>>(src, dst, cur, srcs, E);

    k_gemm1<<<(N + 3) / 4, 256, 0, stream>>>(feat, W1, att_s1, att_d1, bufA, a_s1, a_d1, N);
    k_agg1 <<<(N + 3) / 4, 256, 0, stream>>>(deg, offs, srcs, a_s1, a_d1, bufA, b1, bufB, N);
    k_gemm2<<<(N + 3) / 4, 256, 0, stream>>>(bufB, W2, att_s2, att_d2, bufA, a_s2, a_d2, N);
    k_agg2 <<<(N + 3) / 4, 256, 0, stream>>>(deg, offs, srcs, a_s2, a_d2, bufA, b2, label,
                                             out, bins, N);
    k_loss <<<1, 256, 0, stream>>>(bins, out, N);
}